// Round 19
// baseline (48.566 us; speedup 1.0000x reference)
//
#include <hip/hip_runtime.h>
#include <hip/hip_bf16.h>
#include <math.h>
#include <string.h>

#define NB 8
#define NC 256
#define HWSZ 1024
#define NHEAD 8
#define DHEAD 32
#define NGRP 32
#define CPG 8
#define EPSV 1e-5f

typedef float f32x4 __attribute__((ext_vector_type(4)));
typedef float f32x16 __attribute__((ext_vector_type(16)));
typedef short bf16x8 __attribute__((ext_vector_type(8)));

__device__ __forceinline__ unsigned pk2(float a, float b) {
    __hip_bfloat162 h = __float22bfloat162_rn(make_float2(a, b));
    unsigned r;
    memcpy(&r, &h, sizeof(r));
    return r;
}
// truncation pack (RTZ): P >= 0, rel error <= 0.4% downward
__device__ __forceinline__ unsigned pk2t(float a, float b) {
    unsigned ua = __float_as_uint(a), ub = __float_as_uint(b);
    return (ua >> 16) | (ub & 0xFFFF0000u);
}
__device__ __forceinline__ unsigned short f2bf(float x) {
    __hip_bfloat16 h = __float2bfloat16(x);
    unsigned short r;
    memcpy(&r, &h, sizeof(r));
    return r;
}
__device__ __forceinline__ float ex2(float x) { return __builtin_amdgcn_exp2f(x); }

// async global->LDS, 16B per lane; LDS dest = wave-uniform base + lane*16
__device__ __forceinline__ void gload_lds16(const void* g, void* l) {
    __builtin_amdgcn_global_load_lds(
        (const __attribute__((address_space(1))) unsigned int*)g,
        (__attribute__((address_space(3))) unsigned int*)l, 16, 0, 0);
}

// ---------------- prep ----------------
// blocks 0..511: GroupNorm stats + write NORMALIZED bf16 X in MFMA-unit layout
//   xn[which][b][g][p][8c]. blocks 512..639: weight fp32->bf16 convert.
__global__ void prep_kernel(const float* __restrict__ xq,
                            const float* __restrict__ xkv,
                            const float* __restrict__ gq_scale,
                            const float* __restrict__ gq_bias,
                            const float* __restrict__ gkv_scale,
                            const float* __restrict__ gkv_bias,
                            const float* __restrict__ Wq,
                            const float* __restrict__ Wkv,
                            const float* __restrict__ Wout,
                            unsigned short* __restrict__ xnq,
                            unsigned short* __restrict__ xnkv,
                            unsigned short* __restrict__ wqb,
                            unsigned short* __restrict__ wkvb,
                            unsigned short* __restrict__ woutb) {
    if (blockIdx.x < 512) {
        int idx = blockIdx.x;            // which*256 + b*32 + g
        int which = idx >> 8;
        int b = (idx >> 5) & 7;
        int g = idx & 31;
        const float* x = which ? xkv : xq;
        const float4* xb = (const float4*)(x + ((size_t)(b * NC + g * CPG)) * HWSZ);
        float s = 0.f, ss = 0.f;
        for (int i = threadIdx.x; i < (CPG * HWSZ) / 4; i += 256) {
            float4 v = xb[i];
            s += v.x + v.y + v.z + v.w;
            ss += v.x * v.x + v.y * v.y + v.z * v.z + v.w * v.w;
        }
        #pragma unroll
        for (int off = 32; off > 0; off >>= 1) {
            s += __shfl_down(s, off);
            ss += __shfl_down(ss, off);
        }
        __shared__ float red[10];
        int wid = threadIdx.x >> 6;
        if ((threadIdx.x & 63) == 0) { red[wid * 2] = s; red[wid * 2 + 1] = ss; }
        __syncthreads();
        if (threadIdx.x == 0) {
            float S = red[0] + red[2] + red[4] + red[6];
            float SS = red[1] + red[3] + red[5] + red[7];
            float mean = S * (1.f / (CPG * HWSZ));
            float var = SS * (1.f / (CPG * HWSZ)) - mean * mean;
            red[8] = mean;
            red[9] = rsqrtf(var + EPSV);
        }
        __syncthreads();
        const float mean = red[8], rstd = red[9];
        const float* scp = which ? gkv_scale : gq_scale;
        const float* bip = which ? gkv_bias : gq_bias;
        float a[8], bb[8];
        #pragma unroll
        for (int u = 0; u < 8; ++u) {
            int c = g * 8 + u;
            a[u] = rstd * scp[c];
            bb[u] = bip[c] - mean * a[u];
        }
        const int p0 = threadIdx.x * 4;
        f32x4 rowv[8];
        #pragma unroll
        for (int u = 0; u < 8; ++u)
            rowv[u] = *(const f32x4*)&x[((size_t)(b * NC + g * 8 + u)) * HWSZ + p0];
        unsigned short* xt = (which ? xnkv : xnq)
                           + (((size_t)b * NGRP + g) * HWSZ) * 8;
        #pragma unroll
        for (int pi = 0; pi < 4; ++pi) {
            uint4 o;
            o.x = pk2(rowv[0][pi] * a[0] + bb[0], rowv[1][pi] * a[1] + bb[1]);
            o.y = pk2(rowv[2][pi] * a[2] + bb[2], rowv[3][pi] * a[3] + bb[3]);
            o.z = pk2(rowv[4][pi] * a[4] + bb[4], rowv[5][pi] * a[5] + bb[5]);
            o.w = pk2(rowv[6][pi] * a[6] + bb[6], rowv[7][pi] * a[7] + bb[7]);
            *(uint4*)&xt[(size_t)(p0 + pi) * 8] = o;
        }
    } else {
        int gid = (blockIdx.x - 512) * 256 + threadIdx.x;
        int i0 = gid * 8;
        const float* src; unsigned short* dst; int off; float sc = 1.f;
        if (i0 < 65536)       { src = Wq;   dst = wqb;   off = i0;          sc = 0.0625f * 1.44269504088896f; }
        else if (i0 < 196608) { src = Wkv;  dst = wkvb;  off = i0 - 65536; }
        else                  { src = Wout; dst = woutb; off = i0 - 196608; }
        float4 v0 = *(const float4*)&src[off];
        float4 v1 = *(const float4*)&src[off + 4];
        uint4 o;
        o.x = pk2(v0.x * sc, v0.y * sc); o.y = pk2(v0.z * sc, v0.w * sc);
        o.z = pk2(v1.x * sc, v1.y * sc); o.w = pk2(v1.z * sc, v1.w * sc);
        *(uint4*)&dst[off] = o;
    }
}

// ---------------- fused QKV GEMM: pure-copy B staging, A reg-preloaded ----------------
// V slot mapping changed: within each 16-key block, key k stored at slot
// swap23(k) (bits 2<->3) -- the sigma for the 32x32x16 attention PV.
__global__ __launch_bounds__(256) void qkv_gemm_kernel(
        const unsigned short* __restrict__ wqb,
        const unsigned short* __restrict__ wkvb,
        const unsigned short* __restrict__ xnq,
        const unsigned short* __restrict__ xnkv,
        unsigned short* __restrict__ qbuf,
        unsigned short* __restrict__ kbuf,
        unsigned short* __restrict__ vbuf) {
    __shared__ unsigned short Bs[64 * 256];
    const int tid = threadIdx.x;
    const int l16 = tid & 15, g = (tid >> 4) & 3, w = tid >> 6;
    const int y = blockIdx.y;
    const bool isQ = y < 4;
    const int o0 = (isQ ? y : y - 4) * 64;
    const size_t prow0 = (size_t)blockIdx.x * 64;
    const int b = (int)(prow0 >> 10);
    const int pp = (int)(prow0 & 1023);

    const unsigned short* Asrc = (isQ ? wqb : wkvb)
                               + ((size_t)o0 + 16 * w + l16) * NC;
    bf16x8 af[8];
    #pragma unroll
    for (int kk = 0; kk < 8; ++kk)
        af[kk] = *(const bf16x8*)&Asrc[(kk * 4 + g) << 3];

    const unsigned short* Xn = (isQ ? xnq : xnkv) + (size_t)b * NGRP * HWSZ * 8;
    const int prow = tid & 63, gu0 = tid >> 6;
    #pragma unroll
    for (int i = 0; i < 8; ++i) {
        int gu = gu0 + i * 4;
        uint4 v = *(const uint4*)&Xn[((size_t)gu * HWSZ + pp + prow) * 8];
        int ds = prow * 256 + ((gu ^ (prow & 7)) << 3);
        *(uint4*)&Bs[ds] = v;
    }
    __syncthreads();

    f32x4 acc[4] = {};
    const int asw = l16 & 7;
    #pragma unroll
    for (int kk = 0; kk < 8; ++kk) {
        const int koff = ((kk * 4 + g) ^ asw) << 3;
        #pragma unroll
        for (int j = 0; j < 4; ++j) {
            bf16x8 bfr = *(const bf16x8*)&Bs[(j * 16 + l16) * 256 + koff];
            acc[j] = __builtin_amdgcn_mfma_f32_16x16x32_bf16(af[kk], bfr, acc[j], 0, 0, 0);
        }
    }

    if (isQ) {
        int ob_ = o0 + 16 * w + 4 * g;
        int n = ob_ >> 5, d0 = ob_ & 31;
        unsigned short* dst = qbuf + ((size_t)(b * NHEAD + n) * HWSZ) * DHEAD + d0;
        #pragma unroll
        for (int j = 0; j < 4; ++j) {
            int p = pp + 16 * j + l16;
            uint2 st2;
            st2.x = pk2(acc[j][0], acc[j][1]);
            st2.y = pk2(acc[j][2], acc[j][3]);
            *(uint2*)&dst[(size_t)p * DHEAD] = st2;
        }
    } else {
        int n = o0 >> 6;
        int d0 = 16 * (w & 1) + 4 * g;
        if (w < 2) {   // K
            unsigned short* dst = kbuf + ((size_t)(b * NHEAD + n) * HWSZ) * DHEAD + d0;
            #pragma unroll
            for (int j = 0; j < 4; ++j) {
                int p = pp + 16 * j + l16;
                uint2 st2;
                st2.x = pk2(acc[j][0], acc[j][1]);
                st2.y = pk2(acc[j][2], acc[j][3]);
                *(uint2*)&dst[(size_t)p * DHEAD] = st2;
            }
        } else {
            // V -> [b][n][d][p'] : key k at slot swap23(k&15) within 16-block
            unsigned short* dst = vbuf + ((size_t)(b * NHEAD + n) * DHEAD + d0) * HWSZ;
            int slot = (l16 & 3) | ((l16 & 4) << 1) | ((l16 & 8) >> 1);
            #pragma unroll
            for (int j = 0; j < 4; ++j) {
                int p = pp + 16 * j + slot;
                #pragma unroll
                for (int r = 0; r < 4; ++r)
                    dst[(size_t)r * HWSZ + p] = f2bf(acc[j][r]);
            }
        }
    }
}

// ---------------- out GEMM: A (obuf rows) preloaded in regs, B (Wout) staged ----
__global__ __launch_bounds__(256) void out_gemm_kernel(
        const unsigned short* __restrict__ Abase,
        const unsigned short* __restrict__ Bbase,
        const float* __restrict__ bias_out,
        const float* __restrict__ resid,
        float* __restrict__ out0) {
    __shared__ unsigned short Bs[64 * 256];
    const int tid = threadIdx.x;
    const int l16 = tid & 15, g = (tid >> 4) & 3, w = tid >> 6;
    const int o0 = blockIdx.y * 64;
    const size_t prow0 = (size_t)blockIdx.x * 64;

    const unsigned short* Asrc = Abase + (prow0 + 16 * w + l16) * NC;
    bf16x8 af[8];
    #pragma unroll
    for (int kk = 0; kk < 8; ++kk)
        af[kk] = *(const bf16x8*)&Asrc[(kk * 4 + g) << 3];

    const unsigned short* Bsrc = Bbase + (size_t)o0 * NC;
    #pragma unroll
    for (int it = 0; it < 4; ++it) {
        int idx = tid + it * 256;
        int row = idx >> 4, seg = idx & 15;
        #pragma unroll
        for (int h = 0; h < 2; ++h) {
            int sg = seg * 2 + h;
            int ds = row * 256 + ((sg ^ (row & 7)) << 3);
            *(uint4*)&Bs[ds] = *(const uint4*)&Bsrc[(size_t)row * NC + sg * 8];
        }
    }
    __syncthreads();

    f32x4 acc[4] = {};
    const int asw = l16 & 7;
    #pragma unroll
    for (int kk = 0; kk < 8; ++kk) {
        const int koff = ((kk * 4 + g) ^ asw) << 3;
        #pragma unroll
        for (int j = 0; j < 4; ++j) {
            bf16x8 b = *(const bf16x8*)&Bs[(j * 16 + l16) * 256 + koff];
            acc[j] = __builtin_amdgcn_mfma_f32_16x16x32_bf16(af[kk], b, acc[j], 0, 0, 0);
        }
    }
    const int b = (int)(prow0 >> 10);
    const int pp = (int)(prow0 & 1023);
    int p_b = pp + 16 * w + 4 * g;
    #pragma unroll
    for (int j = 0; j < 4; ++j) {
        int o = o0 + 16 * j + l16;
        float bo = bias_out[o];
        size_t off = ((size_t)b * NC + o) * HWSZ + p_b;
        float4 rs = *(const float4*)&resid[off];
        float4 vst = make_float4(acc[j][0] + bo + rs.x, acc[j][1] + bo + rs.y,
                                 acc[j][2] + bo + rs.z, acc[j][3] + bo + rs.w);
        *(float4*)&out0[off] = vst;
    }
}

// ---------------- MFMA flash attention: 32x32x16, 32 queries/wave ----------------
// Wave = 32 queries x 1024 keys; 64-key tiles. Per tile: 4 QK + 4 PV + 4 accl
// MFMAs (32x32x16) and only 8 ds_read_b128 for 32 queries (half of the 16x16
// formulation's LDS traffic -- the measured bottleneck). LDS layouts unit-major
// (K[4 d-units][64 keys], V[8 k-units][32 d]) so every b128 is contiguous.
// P fragments = S-tile regs [8m..8m+7] packed in order (uniform across lanes),
// valid because V is stored with sigma = swap-bits-2/3 of the within-16 key
// index (applied in qkv) matching the 32x32 D-layout row formula.
// Max-free softmax (exact here), l via ones-MFMA, counted vmcnt(2) staging.
__global__ __launch_bounds__(256) void attn_mfma_kernel(
        const unsigned short* __restrict__ qb,
        const unsigned short* __restrict__ kb,
        const unsigned short* __restrict__ vb,
        unsigned short* __restrict__ ob) {
    __shared__ unsigned short KV[3][4096];   // [buf][K: 0..2047 | V: 2048..4095]
    const int tid = threadIdx.x;
    const int w = tid >> 6, lane = tid & 63;
    const int l31 = lane & 31, h = lane >> 5;
    // 512 blocks: all 8 q-blocks of one bn on the same XCD
    const int F = blockIdx.y * 8 + blockIdx.x;
    const int bn = (F & 7) * 8 + ((F >> 3) & 7);
    const int qblk = F >> 6;                 // 0..7
    const int qp = qblk * 128 + w * 32 + l31;

    // Q fragments: B operand, col=q=lane&31, k-rows (lane>>5)*8+e
    const unsigned short* qsrc = qb + ((size_t)bn * HWSZ + qp) * DHEAD + h * 8;
    bf16x8 qf0 = *(const bf16x8*)qsrc;
    bf16x8 qf1 = *(const bf16x8*)(qsrc + 16);

    // staging sources (LDS dest linear: chunk tid*16B)
    // K chunk tid: u = tid>>6 (=w), key = tid&63 -> K_lds[u][key][8]
    const unsigned short* ksrc = kb + (size_t)bn * HWSZ * DHEAD
                               + (size_t)lane * DHEAD + w * 8;
    // V chunk tid: ku = tid>>5, d = tid&31 -> V_lds[ku][d][8]
    const int vku = tid >> 5, vd = tid & 31;
    const unsigned short* vsrc = vb + (size_t)bn * DHEAD * HWSZ
                               + (size_t)vd * HWSZ + vku * 8;
    unsigned short* lk = &KV[0][0] + w * 512;
    unsigned short* lv = &KV[0][2048] + w * 512;

#define STAGE(t) do {                                                        \
        int b3_ = (t) % 3; int ti_ = (t) & 15;                               \
        gload_lds16(ksrc + (size_t)ti_ * 64 * DHEAD, lk + b3_ * 4096);       \
        gload_lds16(vsrc + (size_t)ti_ * 64,         lv + b3_ * 4096);       \
    } while (0)

    f32x16 accO = {};
    f32x16 accl = {};
    const f32x16 z16 = {};

    const unsigned on2 = 0x3F803F80u;    // two bf16 1.0
    uint4 onev = make_uint4(on2, on2, on2, on2);
    bf16x8 ones;
    memcpy(&ones, &onev, sizeof(ones));

    STAGE(0);
    STAGE(1);

    #pragma unroll
    for (int t = 0; t < 16; ++t) {
        const int cur = t % 3;
        asm volatile("s_waitcnt vmcnt(2)" ::: "memory");
        __builtin_amdgcn_s_barrier();
        STAGE(t + 2);

        const unsigned short* Kb = &KV[cur][0];
        const unsigned short* Vb = &KV[cur][2048];
        // K A-frags: row=key=lane&31 (+32 for 2nd S tile), cols d-unit
        bf16x8 ka00 = *(const bf16x8*)&Kb[((h)     * 64 + l31)      * 8];
        bf16x8 ka01 = *(const bf16x8*)&Kb[((2 + h) * 64 + l31)      * 8];
        bf16x8 ka10 = *(const bf16x8*)&Kb[((h)     * 64 + 32 + l31) * 8];
        bf16x8 ka11 = *(const bf16x8*)&Kb[((2 + h) * 64 + 32 + l31) * 8];

        f32x16 s1 = __builtin_amdgcn_mfma_f32_32x32x16_bf16(ka00, qf0, z16, 0, 0, 0);
        s1 = __builtin_amdgcn_mfma_f32_32x32x16_bf16(ka01, qf1, s1, 0, 0, 0);
        f32x16 s2 = __builtin_amdgcn_mfma_f32_32x32x16_bf16(ka10, qf0, z16, 0, 0, 0);
        s2 = __builtin_amdgcn_mfma_f32_32x32x16_bf16(ka11, qf1, s2, 0, 0, 0);

        // exp (max-free, exact) + pack: P frag m = S regs [8m..8m+7] in order
        uint4 pw0, pw1, pw2, pw3;
        pw0.x = pk2t(ex2(s1[0]),  ex2(s1[1]));  pw0.y = pk2t(ex2(s1[2]),  ex2(s1[3]));
        pw0.z = pk2t(ex2(s1[4]),  ex2(s1[5]));  pw0.w = pk2t(ex2(s1[6]),  ex2(s1[7]));
        pw1.x = pk2t(ex2(s1[8]),  ex2(s1[9]));  pw1.y = pk2t(ex2(s1[10]), ex2(s1[11]));
        pw1.z = pk2t(ex2(s1[12]), ex2(s1[13])); pw1.w = pk2t(ex2(s1[14]), ex2(s1[15]));
        pw2.x = pk2t(ex2(s2[0]),  ex2(s2[1]));  pw2.y = pk2t(ex2(s2[2]),  ex2(s2[3]));
        pw2.z = pk2t(ex2(s2[4]),  ex2(s2[5]));  pw2.w = pk2t(ex2(s2[6]),  ex2(s2[7]));
        pw3.x = pk2t(ex2(s2[8]),  ex2(s2[9]));  pw3.y = pk2t(ex2(s2[10]), ex2(s2[11]));
        pw3.z = pk2t(ex2(s2[12]), ex2(s2[13])); pw3.w = pk2t(ex2(s2[14]), ex2(s2[15]));
        bf16x8 pf0, pf1, pf2, pf3;
        memcpy(&pf0, &pw0, sizeof(pf0));
        memcpy(&pf1, &pw1, sizeof(pf1));
        memcpy(&pf2, &pw2, sizeof(pf2));
        memcpy(&pf3, &pw3, sizeof(pf3));

        // V A-frags: row=d=lane&31, cols k-unit 2m+h (sigma-permuted storage)
        bf16x8 va0 = *(const bf16x8*)&Vb[((0 + h) * 32 + l31) * 8];
        bf16x8 va1 = *(const bf16x8*)&Vb[((2 + h) * 32 + l31) * 8];
        bf16x8 va2 = *(const bf16x8*)&Vb[((4 + h) * 32 + l31) * 8];
        bf16x8 va3 = *(const bf16x8*)&Vb[((6 + h) * 32 + l31) * 8];

        accO = __builtin_amdgcn_mfma_f32_32x32x16_bf16(va0, pf0, accO, 0, 0, 0);
        accO = __builtin_amdgcn_mfma_f32_32x32x16_bf16(va1, pf1, accO, 0, 0, 0);
        accO = __builtin_amdgcn_mfma_f32_32x32x16_bf16(va2, pf2, accO, 0, 0, 0);
        accO = __builtin_amdgcn_mfma_f32_32x32x16_bf16(va3, pf3, accO, 0, 0, 0);
        accl = __builtin_amdgcn_mfma_f32_32x32x16_bf16(ones, pf0, accl, 0, 0, 0);
        accl = __builtin_amdgcn_mfma_f32_32x32x16_bf16(ones, pf1, accl, 0, 0, 0);
        accl = __builtin_amdgcn_mfma_f32_32x32x16_bf16(ones, pf2, accl, 0, 0, 0);
        accl = __builtin_amdgcn_mfma_f32_32x32x16_bf16(ones, pf3, accl, 0, 0, 0);
    }
#undef STAGE

    // accl rows all equal = softmax denominator for query l31
    float invl = 1.f / accl[0];

    // O^T: col=q, row d = (reg&3)+8*(reg>>2)+4h
    const int b = bn >> 3, n = bn & 7;
    unsigned short* dst = ob + ((size_t)b * HWSZ + qp) * NC + n * DHEAD + 4 * h;
    #pragma unroll
    for (int gr = 0; gr < 4; ++gr) {
        uint2 st2;
        st2.x = pk2(accO[gr * 4 + 0] * invl, accO[gr * 4 + 1] * invl);
        st2.y = pk2(accO[gr * 4 + 2] * invl, accO[gr * 4 + 3] * invl);
        *(uint2*)&dst[8 * gr] = st2;
    }
}

extern "C" void kernel_launch(void* const* d_in, const int* in_sizes, int n_in,
                              void* d_out, int out_size, void* d_ws, size_t ws_size,
                              hipStream_t stream) {
    const float* input_q  = (const float*)d_in[0];
    const float* input_kv = (const float*)d_in[1];
    const float* gq_scale = (const float*)d_in[2];
    const float* gq_bias  = (const float*)d_in[3];
    const float* gkv_scale = (const float*)d_in[4];
    const float* gkv_bias  = (const float*)d_in[5];
    const float* Wq   = (const float*)d_in[6];
    const float* Wkv  = (const float*)d_in[7];
    const float* Wout = (const float*)d_in[8];
    const float* bout = (const float*)d_in[9];
    float* out = (float*)d_out;

    char* ws = (char*)d_ws;
    unsigned short* wqb   = (unsigned short*)(ws + 16384);        // 128 KB
    unsigned short* wkvb  = (unsigned short*)(ws + 16384 + 131072);        // 256 KB
    unsigned short* woutb = (unsigned short*)(ws + 16384 + 131072 + 262144); // 128 KB
    const size_t MB = 1024 * 1024;
    unsigned short* xnq  = (unsigned short*)(ws + 1 * MB);   // 4 MB  [b][g][p][8c]
    unsigned short* xnkv = (unsigned short*)(ws + 5 * MB);   // 4 MB  [b][g][p][8c]
    unsigned short* qbuf = (unsigned short*)(ws + 9 * MB);   // 4 MB  [b][n][p][d]
    unsigned short* kbuf = (unsigned short*)(ws + 13 * MB);  // 4 MB  [b][n][p][d]
    unsigned short* vbuf = (unsigned short*)(ws + 17 * MB);  // 4 MB  [b][n][d][p'] sigma(swap23)
    unsigned short* obuf = (unsigned short*)(ws + 21 * MB);  // 4 MB  [b][p][c]

    prep_kernel<<<640, 256, 0, stream>>>(
        input_q, input_kv, gq_scale, gq_bias, gkv_scale, gkv_bias,
        Wq, Wkv, Wout, xnq, xnkv, wqb, wkvb, woutb);
    qkv_gemm_kernel<<<dim3(128, 12), 256, 0, stream>>>(
        wqb, wkvb, xnq, xnkv, qbuf, kbuf, vbuf);
    attn_mfma_kernel<<<dim3(8, 64), 256, 0, stream>>>(qbuf, kbuf, vbuf, obuf);
    out_gemm_kernel<<<dim3(128, 4), 256, 0, stream>>>(obuf, woutb, bout, input_q, out);
}